// Round 1
// baseline (1139.228 us; speedup 1.0000x reference)
//
#include <hip/hip_runtime.h>
#include <stdint.h>

typedef unsigned short u16;
typedef __attribute__((ext_vector_type(8))) short bf16x8;
typedef __attribute__((ext_vector_type(4))) float f32x4;

__device__ __forceinline__ u16 f2bf(float f) {
  union { float f; uint32_t u; } v; v.f = f;
  uint32_t u = v.u;
  return (u16)((u + 0x7fffu + ((u >> 16) & 1u)) >> 16);
}

__device__ __forceinline__ void gl_lds16(const void* g, void* l) {
  __builtin_amdgcn_global_load_lds(
      (const __attribute__((address_space(1))) uint32_t*)g,
      (__attribute__((address_space(3))) uint32_t*)l, 16, 0, 0);
}

// ---------------------------------------------------------------------------
// Conv feature extractor: 8 VALID convs (k=1..8), relu, flatten NCHW-style,
// concat -> feat (1024 x 3264), stored bf16.
// ---------------------------------------------------------------------------
__constant__ int c_off[9] = {0, 1024, 1808, 2384, 2784, 3040, 3184, 3248, 3264};

__global__ __launch_bounds__(256)
void conv_feat(const float* __restrict__ x,
               const float* w1, const float* w2, const float* w3, const float* w4,
               const float* w5, const float* w6, const float* w7, const float* w8,
               const float* __restrict__ cb, u16* __restrict__ feat) {
  __shared__ float xs[512];
  const int b = blockIdx.x, t = threadIdx.x;
  xs[t]       = x[(size_t)b * 512 + t];
  xs[t + 256] = x[(size_t)b * 512 + 256 + t];
  __syncthreads();
  const float* ws[8] = {w1, w2, w3, w4, w5, w6, w7, w8};
  for (int o = t; o < 3264; o += 256) {
    int kidx = 0;
    while (o >= c_off[kidx + 1]) ++kidx;
    const int ks = kidx + 1;         // kernel size
    const int s  = 8 - kidx;         // output spatial dim = 9 - ks
    const int r  = o - c_off[kidx];
    const int f   = r / (s * s);
    const int rem = r - f * s * s;
    const int oi  = rem / s;
    const int oj  = rem - oi * s;
    const float* w = ws[kidx] + (size_t)f * 8 * ks * ks;   // w[f][c][di][dj]
    float acc = cb[kidx * 16 + f];
    for (int c = 0; c < 8; ++c)
      for (int di = 0; di < ks; ++di)
        for (int dj = 0; dj < ks; ++dj)
          acc += xs[(oi + di) * 64 + (oj + dj) * 8 + c] * w[(c * ks + di) * ks + dj];
    feat[(size_t)b * 3264 + o] = f2bf(acc > 0.f ? acc : 0.f);
  }
}

// ---------------------------------------------------------------------------
// Transpose + fp32->bf16 convert: src (R x C) f32 -> dst (Cp x R) bf16,
// zero-fill rows >= C. grid = (Cp/64, R/64).
// ---------------------------------------------------------------------------
__global__ __launch_bounds__(256)
void transpose_bf16(const float* __restrict__ src, u16* __restrict__ dst,
                    int R, int C) {
  __shared__ float tile[64][65];
  const int t = threadIdx.x;
  const int rb = blockIdx.y << 6, cbs = blockIdx.x << 6;
  for (int i = 0; i < 16; ++i) {
    const int idx = t + (i << 8);
    const int r = idx >> 6, c = idx & 63;
    float v = 0.f;
    if (cbs + c < C) v = src[(size_t)(rb + r) * C + cbs + c];
    tile[r][c] = v;
  }
  __syncthreads();
  for (int i = 0; i < 16; ++i) {
    const int idx = t + (i << 8);
    const int c = idx >> 6, r = idx & 63;
    dst[(size_t)(cbs + c) * R + rb + r] = f2bf(tile[r][c]);
  }
}

// ---------------------------------------------------------------------------
// W_eff = (W + 2.0 * loraA @ loraB) * (W != 0), written TRANSPOSED as bf16:
// Wt[n][k] (4096 x 4096). K(lora)=64 fits one tile. grid = (64, 64).
// ---------------------------------------------------------------------------
__global__ __launch_bounds__(256)
void weff_kernel(const float* __restrict__ W, const float* __restrict__ lA,
                 const float* __restrict__ lB, u16* __restrict__ Wt) {
  __shared__ float at[64][65];   // at[k_local][r]
  __shared__ float bt[64][65];   // bt[n_local][r]
  __shared__ float wt[64][65];   // wt[k_local][n_local]
  const int t = threadIdx.x;
  const int kb = blockIdx.y << 6, nb = blockIdx.x << 6;
  for (int i = 0; i < 16; ++i) {
    const int idx = t + (i << 8);
    const int r0 = idx >> 6, c0 = idx & 63;
    at[r0][c0] = lA[(size_t)(kb + r0) * 64 + c0];          // A[k][r]
    bt[c0][r0] = lB[(size_t)r0 * 4096 + nb + c0];          // B[r][n] -> bt[n][r]
    wt[r0][c0] = W[(size_t)(kb + r0) * 4096 + nb + c0];
  }
  __syncthreads();
  const int tk = t & 15, tn = t >> 4;
  float s[4][4] = {};
  for (int r = 0; r < 64; ++r) {
    float a[4], b[4];
    for (int i = 0; i < 4; ++i) a[i] = at[tk * 4 + i][r];
    for (int j = 0; j < 4; ++j) b[j] = bt[tn * 4 + j][r];
    for (int i = 0; i < 4; ++i)
      for (int j = 0; j < 4; ++j)
        s[i][j] += a[i] * b[j];
  }
  for (int j = 0; j < 4; ++j) {
    const int nl = tn * 4 + j;
    u16 vals[4];
    for (int i = 0; i < 4; ++i) {
      const float wv = wt[tk * 4 + i][nl];
      const float res = (wv != 0.f) ? (wv + 2.0f * s[i][j]) : 0.f;
      vals[i] = f2bf(res);
    }
    ushort4 pack = make_ushort4(vals[0], vals[1], vals[2], vals[3]);
    *(ushort4*)&Wt[(size_t)(nb + nl) * 4096 + kb + tk * 4] = pack;
  }
}

// ---------------------------------------------------------------------------
// m97-style bf16 MFMA GEMM: C(M x N) = A(M x K, bf16 row-major) @ B(K x N)
// with B given transposed: Bt[n][k] bf16. 128x128 tile, BK=64, 256 threads,
// 4 waves each computing 64x64 via 4x4 16x16x32 MFMAs.
// EPI 0: relu(acc + bias[n]) -> outf (f32) + outb (bf16)      [E stage]
// EPI 1: relu(acc + st_in[m][n]) -> outf + outb               [recurrent]
// EPI 2: acc + bias[n] -> outf, guarded n < nvalid            [output]
// ---------------------------------------------------------------------------
template<int EPI>
__global__ __launch_bounds__(256)
void gemm128(const u16* __restrict__ A, int lda,
             const u16* __restrict__ Bt, int ldb, int K,
             const float* __restrict__ bias,
             const float* __restrict__ st_in, int st_ld,
             float* __restrict__ outf, int outf_ld,
             u16* __restrict__ outb, int outb_ld, int nvalid) {
  __shared__ __align__(16) u16 As[128 * 64];
  __shared__ __align__(16) u16 Bs[128 * 64];
  const int t = threadIdx.x;
  const int w = t >> 6, lane = t & 63;
  const int mb = blockIdx.y << 7, nb = blockIdx.x << 7;
  const int m0 = (w & 1) << 6, n0 = (w >> 1) << 6;
  const int lr = lane & 15, lq = lane >> 4;

  f32x4 acc[4][4] = {};

  const int nk = K >> 6;
  for (int kt = 0; kt < nk; ++kt) {
    const int kb = kt << 6;
    // async stage: 1024 16B chunks per tile; chunk c -> LDS offset c*16,
    // source row c>>3, k-chunk c&7. Dest is wave-base + lane*16 (contiguous).
    for (int i = 0; i < 4; ++i) {
      const int c = (w << 8) + (i << 6) + lane;
      gl_lds16(A  + (size_t)(mb + (c >> 3)) * lda + kb + ((c & 7) << 3),
               (char*)As + c * 16);
      gl_lds16(Bt + (size_t)(nb + (c >> 3)) * ldb + kb + ((c & 7) << 3),
               (char*)Bs + c * 16);
    }
    __syncthreads();
    for (int kk = 0; kk < 2; ++kk) {
      bf16x8 af[4], bf[4];
      for (int i = 0; i < 4; ++i)
        af[i] = *(const bf16x8*)&As[(m0 + (i << 4) + lr) * 64 + (kk << 5) + (lq << 3)];
      for (int j = 0; j < 4; ++j)
        bf[j] = *(const bf16x8*)&Bs[(n0 + (j << 4) + lr) * 64 + (kk << 5) + (lq << 3)];
      for (int i = 0; i < 4; ++i)
        for (int j = 0; j < 4; ++j)
          acc[i][j] = __builtin_amdgcn_mfma_f32_16x16x32_bf16(af[i], bf[j], acc[i][j], 0, 0, 0);
    }
    __syncthreads();
  }

  // epilogue: C/D layout col = lane&15, row = (lane>>4)*4 + reg
  for (int i = 0; i < 4; ++i) {
    for (int j = 0; j < 4; ++j) {
      const int cg = nb + n0 + (j << 4) + lr;
      for (int r = 0; r < 4; ++r) {
        const int rg = mb + m0 + (i << 4) + (lq << 2) + r;
        float v = acc[i][j][r];
        if (EPI == 0) {
          v += bias[cg];
          v = v > 0.f ? v : 0.f;
          outf[(size_t)rg * outf_ld + cg] = v;
          outb[(size_t)rg * outb_ld + cg] = f2bf(v);
        } else if (EPI == 1) {
          v += st_in[(size_t)rg * st_ld + cg];
          v = v > 0.f ? v : 0.f;
          outf[(size_t)rg * outf_ld + cg] = v;
          outb[(size_t)rg * outb_ld + cg] = f2bf(v);
        } else {
          if (cg < nvalid)
            outf[(size_t)rg * outf_ld + cg] = v + bias[cg];
        }
      }
    }
  }
}

// ---------------------------------------------------------------------------
extern "C" void kernel_launch(void* const* d_in, const int* in_sizes, int n_in,
                              void* d_out, int out_size, void* d_ws, size_t ws_size,
                              hipStream_t stream) {
  const float* x     = (const float*)d_in[0];
  const float* cw[8];
  for (int i = 0; i < 8; ++i) cw[i] = (const float*)d_in[1 + i];
  const float* convb = (const float*)d_in[9];
  const float* W     = (const float*)d_in[10];
  const float* lA    = (const float*)d_in[11];
  const float* lB    = (const float*)d_in[12];
  const float* ip_w  = (const float*)d_in[13];
  const float* ip_b  = (const float*)d_in[14];
  const float* out_w = (const float*)d_in[15];
  const float* out_b = (const float*)d_in[16];
  float* out = (float*)d_out;

  char* p = (char*)d_ws;
  u16* feat   = (u16*)p;  p += (size_t)1024 * 3264 * 2;
  u16* ip_wt  = (u16*)p;  p += (size_t)1024 * 3264 * 2;
  u16* out_wt = (u16*)p;  p += (size_t)2048 * 1024 * 2;   // padded to 2048 rows
  u16* Wt     = (u16*)p;  p += (size_t)4096 * 4096 * 2;
  float* st_f[2];
  st_f[0] = (float*)p;    p += (size_t)1024 * 4096 * 4;
  st_f[1] = (float*)p;    p += (size_t)1024 * 4096 * 4;
  u16* st_b[2];
  st_b[0] = (u16*)p;      p += (size_t)1024 * 4096 * 2;
  st_b[1] = (u16*)p;      p += (size_t)1024 * 4096 * 2;

  // Stage 1: conv features (bf16), weight transposes, W_eff
  conv_feat<<<1024, 256, 0, stream>>>(x, cw[0], cw[1], cw[2], cw[3],
                                      cw[4], cw[5], cw[6], cw[7], convb, feat);
  transpose_bf16<<<dim3(16, 51), 256, 0, stream>>>(ip_w, ip_wt, 3264, 1024);
  transpose_bf16<<<dim3(32, 16), 256, 0, stream>>>(out_w, out_wt, 1024, 1968);
  weff_kernel<<<dim3(64, 64), 256, 0, stream>>>(W, lA, lB, Wt);

  // state buffers: zero cols >= 1024 (and everything, cheap) of buffer 0
  hipMemsetAsync(st_f[0], 0, (size_t)1024 * 4096 * 4, stream);
  hipMemsetAsync(st_b[0], 0, (size_t)1024 * 4096 * 2, stream);

  // t=0 collapses to state = relu(E_pad): E = feat @ ip_w + ip_b
  gemm128<0><<<dim3(8, 8), 256, 0, stream>>>(feat, 3264, ip_wt, 3264, 3264,
      ip_b, nullptr, 0, st_f[0], 4096, st_b[0], 4096, 1024);

  // t=1..4: state = relu(state + state @ W_eff), ping-pong buffers
  for (int ts = 1; ts <= 4; ++ts) {
    const int cur = (ts - 1) & 1, nxt = ts & 1;
    gemm128<1><<<dim3(32, 8), 256, 0, stream>>>(st_b[cur], 4096, Wt, 4096, 4096,
        nullptr, st_f[cur], 4096, st_f[nxt], 4096, st_b[nxt], 4096, 4096);
  }

  // output: state[:, 3072:] @ out_w + out_b  (final state in buffer 0)
  gemm128<2><<<dim3(16, 8), 256, 0, stream>>>(st_b[0] + 3072, 4096, out_wt, 1024, 1024,
      out_b, nullptr, 0, out, 1968, nullptr, 0, 1968);
}

// Round 2
// 771.008 us; speedup vs baseline: 1.4776x; 1.4776x over previous
//
#include <hip/hip_runtime.h>
#include <stdint.h>

typedef unsigned short u16;
typedef __attribute__((ext_vector_type(8))) short bf16x8;
typedef __attribute__((ext_vector_type(4))) float f32x4;

__device__ __forceinline__ u16 f2bf(float f) {
  union { float f; uint32_t u; } v; v.f = f;
  uint32_t u = v.u;
  return (u16)((u + 0x7fffu + ((u >> 16) & 1u)) >> 16);
}

__device__ __forceinline__ void gl_lds16(const void* g, void* l) {
  __builtin_amdgcn_global_load_lds(
      (const __attribute__((address_space(1))) uint32_t*)g,
      (__attribute__((address_space(3))) uint32_t*)l, 16, 0, 0);
}

__constant__ int c_off[9] = {0, 1024, 1808, 2384, 2784, 3040, 3184, 3248, 3264};

// ---------------------------------------------------------------------------
// x (1024 x 8 x 8 x 8 f32) -> Xb (1024 x 512 bf16). NHWC row-major flatten is
// exactly the GEMM K-layout k = (i*8+j)*8+c.
// ---------------------------------------------------------------------------
__global__ __launch_bounds__(256)
void x_to_bf16(const float* __restrict__ x, u16* __restrict__ Xb) {
  const int i = blockIdx.x * 256 + threadIdx.x;   // one float4 per thread
  const float4 v = ((const float4*)x)[i];
  ushort4 o = make_ushort4(f2bf(v.x), f2bf(v.y), f2bf(v.z), f2bf(v.w));
  ((ushort4*)Xb)[i] = o;
}

// ---------------------------------------------------------------------------
// Build the implicit-GEMM conv weight matrix, transposed/n-major:
// Wct[o][k] (3328 x 512 bf16, rows >= 3264 stay zero; pre-zeroed by memset).
// For output o = (kidx,f,oi,oj): Wct[o][((oi+di)*8 + oj+dj)*8 + c] = w[f][c][di][dj].
// Also fills bias_c[o] = conv_b[kidx][f].
// ---------------------------------------------------------------------------
__global__ __launch_bounds__(256)
void build_wc(const float* w1, const float* w2, const float* w3, const float* w4,
              const float* w5, const float* w6, const float* w7, const float* w8,
              const float* __restrict__ cb,
              u16* __restrict__ Wct, float* __restrict__ bias_c) {
  const int o = blockIdx.x * 256 + threadIdx.x;
  if (o >= 3264) return;
  const float* ws[8] = {w1, w2, w3, w4, w5, w6, w7, w8};
  int kidx = 0;
  while (o >= c_off[kidx + 1]) ++kidx;
  const int ks = kidx + 1;
  const int s  = 8 - kidx;
  const int r  = o - c_off[kidx];
  const int f   = r / (s * s);
  const int rem = r - f * s * s;
  const int oi  = rem / s;
  const int oj  = rem - oi * s;
  const float* w = ws[kidx] + (size_t)f * 8 * ks * ks;   // w[f][c][di][dj]
  u16* row = Wct + (size_t)o * 512;
  for (int c = 0; c < 8; ++c)
    for (int di = 0; di < ks; ++di)
      for (int dj = 0; dj < ks; ++dj)
        row[((oi + di) * 8 + (oj + dj)) * 8 + c] = f2bf(w[(c * ks + di) * ks + dj]);
  bias_c[o] = cb[kidx * 16 + f];
}

// ---------------------------------------------------------------------------
// Transpose + fp32->bf16 convert: src (R x C) f32 -> dst (Cp x R) bf16,
// zero-fill rows >= C. grid = (Cp/64, R/64).
// ---------------------------------------------------------------------------
__global__ __launch_bounds__(256)
void transpose_bf16(const float* __restrict__ src, u16* __restrict__ dst,
                    int R, int C) {
  __shared__ float tile[64][65];
  const int t = threadIdx.x;
  const int rb = blockIdx.y << 6, cbs = blockIdx.x << 6;
  for (int i = 0; i < 16; ++i) {
    const int idx = t + (i << 8);
    const int r = idx >> 6, c = idx & 63;
    float v = 0.f;
    if (cbs + c < C) v = src[(size_t)(rb + r) * C + cbs + c];
    tile[r][c] = v;
  }
  __syncthreads();
  for (int i = 0; i < 16; ++i) {
    const int idx = t + (i << 8);
    const int c = idx >> 6, r = idx & 63;
    dst[(size_t)(cbs + c) * R + rb + r] = f2bf(tile[r][c]);
  }
}

// ---------------------------------------------------------------------------
// W_eff = (W + 2.0 * loraA @ loraB) * (W != 0), written TRANSPOSED as bf16:
// Wt[n][k] (4096 x 4096). K(lora)=64 fits one tile. grid = (64, 64).
// ---------------------------------------------------------------------------
__global__ __launch_bounds__(256)
void weff_kernel(const float* __restrict__ W, const float* __restrict__ lA,
                 const float* __restrict__ lB, u16* __restrict__ Wt) {
  __shared__ float at[64][65];   // at[k_local][r]
  __shared__ float bt[64][65];   // bt[n_local][r]
  __shared__ float wt[64][65];   // wt[k_local][n_local]
  const int t = threadIdx.x;
  const int kb = blockIdx.y << 6, nb = blockIdx.x << 6;
  for (int i = 0; i < 16; ++i) {
    const int idx = t + (i << 8);
    const int r0 = idx >> 6, c0 = idx & 63;
    at[r0][c0] = lA[(size_t)(kb + r0) * 64 + c0];          // A[k][r]
    bt[c0][r0] = lB[(size_t)r0 * 4096 + nb + c0];          // B[r][n] -> bt[n][r]
    wt[r0][c0] = W[(size_t)(kb + r0) * 4096 + nb + c0];
  }
  __syncthreads();
  const int tk = t & 15, tn = t >> 4;
  float s[4][4] = {};
  for (int r = 0; r < 64; ++r) {
    float a[4], b[4];
    for (int i = 0; i < 4; ++i) a[i] = at[tk * 4 + i][r];
    for (int j = 0; j < 4; ++j) b[j] = bt[tn * 4 + j][r];
    for (int i = 0; i < 4; ++i)
      for (int j = 0; j < 4; ++j)
        s[i][j] += a[i] * b[j];
  }
  for (int j = 0; j < 4; ++j) {
    const int nl = tn * 4 + j;
    u16 vals[4];
    for (int i = 0; i < 4; ++i) {
      const float wv = wt[tk * 4 + i][nl];
      const float res = (wv != 0.f) ? (wv + 2.0f * s[i][j]) : 0.f;
      vals[i] = f2bf(res);
    }
    ushort4 pack = make_ushort4(vals[0], vals[1], vals[2], vals[3]);
    *(ushort4*)&Wt[(size_t)(nb + nl) * 4096 + kb + tk * 4] = pack;
  }
}

// ---------------------------------------------------------------------------
// m97-style bf16 MFMA GEMM: C(M x N) = A(M x K, bf16 row-major) @ B(K x N)
// with B given transposed: Bt[n][k] bf16. 128x128 tile, BK=64, 256 threads,
// 4 waves each computing 64x64 via 4x4 16x16x32 MFMAs.
// EPI 0: relu(acc + bias[n]) -> outf (f32) + outb (bf16)      [E stage]
// EPI 1: relu(acc + st_in[m][n]) -> outf + outb               [recurrent]
// EPI 2: acc + bias[n] -> outf, guarded n < nvalid            [output]
// EPI 3: relu(acc + bias[n]) -> outb only                     [conv feat]
// ---------------------------------------------------------------------------
template<int EPI>
__global__ __launch_bounds__(256)
void gemm128(const u16* __restrict__ A, int lda,
             const u16* __restrict__ Bt, int ldb, int K,
             const float* __restrict__ bias,
             const float* __restrict__ st_in, int st_ld,
             float* __restrict__ outf, int outf_ld,
             u16* __restrict__ outb, int outb_ld, int nvalid) {
  __shared__ __align__(16) u16 As[128 * 64];
  __shared__ __align__(16) u16 Bs[128 * 64];
  const int t = threadIdx.x;
  const int w = t >> 6, lane = t & 63;
  const int mb = blockIdx.y << 7, nb = blockIdx.x << 7;
  const int m0 = (w & 1) << 6, n0 = (w >> 1) << 6;
  const int lr = lane & 15, lq = lane >> 4;

  f32x4 acc[4][4] = {};

  const int nk = K >> 6;
  for (int kt = 0; kt < nk; ++kt) {
    const int kb = kt << 6;
    for (int i = 0; i < 4; ++i) {
      const int c = (w << 8) + (i << 6) + lane;
      gl_lds16(A  + (size_t)(mb + (c >> 3)) * lda + kb + ((c & 7) << 3),
               (char*)As + c * 16);
      gl_lds16(Bt + (size_t)(nb + (c >> 3)) * ldb + kb + ((c & 7) << 3),
               (char*)Bs + c * 16);
    }
    __syncthreads();
    for (int kk = 0; kk < 2; ++kk) {
      bf16x8 af[4], bf[4];
      for (int i = 0; i < 4; ++i)
        af[i] = *(const bf16x8*)&As[(m0 + (i << 4) + lr) * 64 + (kk << 5) + (lq << 3)];
      for (int j = 0; j < 4; ++j)
        bf[j] = *(const bf16x8*)&Bs[(n0 + (j << 4) + lr) * 64 + (kk << 5) + (lq << 3)];
      for (int i = 0; i < 4; ++i)
        for (int j = 0; j < 4; ++j)
          acc[i][j] = __builtin_amdgcn_mfma_f32_16x16x32_bf16(af[i], bf[j], acc[i][j], 0, 0, 0);
    }
    __syncthreads();
  }

  // epilogue: C/D layout col = lane&15, row = (lane>>4)*4 + reg
  for (int i = 0; i < 4; ++i) {
    for (int j = 0; j < 4; ++j) {
      const int cg = nb + n0 + (j << 4) + lr;
      for (int r = 0; r < 4; ++r) {
        const int rg = mb + m0 + (i << 4) + (lq << 2) + r;
        float v = acc[i][j][r];
        if (EPI == 0) {
          v += bias[cg];
          v = v > 0.f ? v : 0.f;
          outf[(size_t)rg * outf_ld + cg] = v;
          outb[(size_t)rg * outb_ld + cg] = f2bf(v);
        } else if (EPI == 1) {
          v += st_in[(size_t)rg * st_ld + cg];
          v = v > 0.f ? v : 0.f;
          outf[(size_t)rg * outf_ld + cg] = v;
          outb[(size_t)rg * outb_ld + cg] = f2bf(v);
        } else if (EPI == 2) {
          if (cg < nvalid)
            outf[(size_t)rg * outf_ld + cg] = v + bias[cg];
        } else {
          v += bias[cg];
          v = v > 0.f ? v : 0.f;
          outb[(size_t)rg * outb_ld + cg] = f2bf(v);
        }
      }
    }
  }
}

// ---------------------------------------------------------------------------
extern "C" void kernel_launch(void* const* d_in, const int* in_sizes, int n_in,
                              void* d_out, int out_size, void* d_ws, size_t ws_size,
                              hipStream_t stream) {
  const float* x     = (const float*)d_in[0];
  const float* cw[8];
  for (int i = 0; i < 8; ++i) cw[i] = (const float*)d_in[1 + i];
  const float* convb = (const float*)d_in[9];
  const float* W     = (const float*)d_in[10];
  const float* lA    = (const float*)d_in[11];
  const float* lB    = (const float*)d_in[12];
  const float* ip_w  = (const float*)d_in[13];
  const float* ip_b  = (const float*)d_in[14];
  const float* out_w = (const float*)d_in[15];
  const float* out_b = (const float*)d_in[16];
  float* out = (float*)d_out;

  char* p = (char*)d_ws;
  u16* feat   = (u16*)p;  p += (size_t)1024 * 3328 * 2;   // lda 3328 (N padded)
  u16* ip_wt  = (u16*)p;  p += (size_t)1024 * 3264 * 2;
  u16* out_wt = (u16*)p;  p += (size_t)2048 * 1024 * 2;   // padded to 2048 rows
  u16* Wt     = (u16*)p;  p += (size_t)4096 * 4096 * 2;
  float* st_f[2];
  st_f[0] = (float*)p;    p += (size_t)1024 * 4096 * 4;
  st_f[1] = (float*)p;    p += (size_t)1024 * 4096 * 4;
  u16* st_b[2];
  st_b[0] = (u16*)p;      p += (size_t)1024 * 4096 * 2;
  st_b[1] = (u16*)p;      p += (size_t)1024 * 4096 * 2;

  // Conv-prep buffers alias st_f[1]: last read at the conv GEMM, st_f[1] is
  // first written at the t=1 recurrent GEMM (strictly later on the stream).
  char* q = (char*)st_f[1];
  u16* Xb       = (u16*)q;  q += (size_t)1024 * 512 * 2;
  u16* Wct      = (u16*)q;  q += (size_t)3328 * 512 * 2;
  float* bias_c = (float*)q;

  // --- conv prep: flatten x to bf16, build implicit-GEMM weight matrix ---
  x_to_bf16<<<512, 256, 0, stream>>>(x, Xb);
  hipMemsetAsync(Wct, 0, (size_t)3328 * 512 * 2, stream);
  hipMemsetAsync(bias_c, 0, (size_t)3328 * 4, stream);
  build_wc<<<13, 256, 0, stream>>>(cw[0], cw[1], cw[2], cw[3],
                                   cw[4], cw[5], cw[6], cw[7], convb, Wct, bias_c);

  // --- weight transposes + W_eff ---
  transpose_bf16<<<dim3(16, 51), 256, 0, stream>>>(ip_w, ip_wt, 3264, 1024);
  transpose_bf16<<<dim3(32, 16), 256, 0, stream>>>(out_w, out_wt, 1024, 1968);
  weff_kernel<<<dim3(64, 64), 256, 0, stream>>>(W, lA, lB, Wt);

  hipMemsetAsync(st_f[0], 0, (size_t)1024 * 4096 * 4, stream);
  hipMemsetAsync(st_b[0], 0, (size_t)1024 * 4096 * 2, stream);

  // --- conv as MFMA GEMM: feat = relu(Xb @ Wc + bias_c), bf16 out ---
  gemm128<3><<<dim3(26, 8), 256, 0, stream>>>(Xb, 512, Wct, 512, 512,
      bias_c, nullptr, 0, nullptr, 0, feat, 3328, 3328);

  // t=0 collapses to state = relu(E_pad): E = feat @ ip_w + ip_b
  gemm128<0><<<dim3(8, 8), 256, 0, stream>>>(feat, 3328, ip_wt, 3264, 3264,
      ip_b, nullptr, 0, st_f[0], 4096, st_b[0], 4096, 1024);

  // t=1..4: state = relu(state + state @ W_eff), ping-pong buffers
  for (int ts = 1; ts <= 4; ++ts) {
    const int cur = (ts - 1) & 1, nxt = ts & 1;
    gemm128<1><<<dim3(32, 8), 256, 0, stream>>>(st_b[cur], 4096, Wt, 4096, 4096,
        nullptr, st_f[cur], 4096, st_f[nxt], 4096, st_b[nxt], 4096, 4096);
  }

  // output: state[:, 3072:] @ out_w + out_b  (final state in buffer 0)
  gemm128<2><<<dim3(16, 8), 256, 0, stream>>>(st_b[0] + 3072, 4096, out_wt, 1024, 1024,
      out_b, nullptr, 0, out, 1968, nullptr, 0, 1968);
}

// Round 3
// 643.262 us; speedup vs baseline: 1.7710x; 1.1986x over previous
//
#include <hip/hip_runtime.h>
#include <stdint.h>

typedef unsigned short u16;
typedef __attribute__((ext_vector_type(8))) short bf16x8;
typedef __attribute__((ext_vector_type(4))) float f32x4;

__device__ __forceinline__ u16 f2bf(float f) {
  union { float f; uint32_t u; } v; v.f = f;
  uint32_t u = v.u;
  return (u16)((u + 0x7fffu + ((u >> 16) & 1u)) >> 16);
}

__device__ __forceinline__ void gl_lds16(const void* g, void* l) {
  __builtin_amdgcn_global_load_lds(
      (const __attribute__((address_space(1))) uint32_t*)g,
      (__attribute__((address_space(3))) uint32_t*)l, 16, 0, 0);
}

__constant__ int c_off[9] = {0, 1024, 1808, 2384, 2784, 3040, 3184, 3248, 3264};

// ---------------------------------------------------------------------------
// x (1024 x 8 x 8 x 8 f32) -> Xb (1024 x 512 bf16). NHWC row-major flatten is
// exactly the GEMM K-layout k = (i*8+j)*8+c.
// ---------------------------------------------------------------------------
__global__ __launch_bounds__(256)
void x_to_bf16(const float* __restrict__ x, u16* __restrict__ Xb) {
  const int i = blockIdx.x * 256 + threadIdx.x;   // one float4 per thread
  const float4 v = ((const float4*)x)[i];
  ushort4 o = make_ushort4(f2bf(v.x), f2bf(v.y), f2bf(v.z), f2bf(v.w));
  ((ushort4*)Xb)[i] = o;
}

// ---------------------------------------------------------------------------
// Build the implicit-GEMM conv weight matrix, transposed/n-major:
// Wct[o][k] (3328 x 512 bf16, rows >= 3264 stay zero; pre-zeroed by memset).
// ONE BLOCK PER OUTPUT COLUMN o (R2: was 13 blocks -> 128us latency-bound;
// 3264 blocks hides the scalar scatter latency).
// ---------------------------------------------------------------------------
__global__ __launch_bounds__(256)
void build_wc(const float* w1, const float* w2, const float* w3, const float* w4,
              const float* w5, const float* w6, const float* w7, const float* w8,
              const float* __restrict__ cb,
              u16* __restrict__ Wct, float* __restrict__ bias_c) {
  const int o = blockIdx.x;
  const int t = threadIdx.x;
  const float* ws[8] = {w1, w2, w3, w4, w5, w6, w7, w8};
  int kidx = 0;
  while (o >= c_off[kidx + 1]) ++kidx;
  const int ks = kidx + 1;
  const int s  = 8 - kidx;
  const int r  = o - c_off[kidx];
  const int f   = r / (s * s);
  const int rem = r - f * s * s;
  const int oi  = rem / s;
  const int oj  = rem - oi * s;
  const float* w = ws[kidx] + (size_t)f * 8 * ks * ks;   // w[f][c][di][dj]
  u16* row = Wct + (size_t)o * 512;
  const int ne = 8 * ks * ks;
  for (int e = t; e < ne; e += 256) {
    const int c  = e / (ks * ks);
    const int er = e - c * ks * ks;
    const int di = er / ks;
    const int dj = er - di * ks;
    row[((oi + di) * 8 + (oj + dj)) * 8 + c] = f2bf(w[(c * ks + di) * ks + dj]);
  }
  if (t == 0) bias_c[o] = cb[kidx * 16 + f];
}

// ---------------------------------------------------------------------------
// Transpose + fp32->bf16 convert: src (R x C) f32 -> dst (Cp x R) bf16,
// zero-fill rows >= C. grid = (Cp/64, R/64).
// ---------------------------------------------------------------------------
__global__ __launch_bounds__(256)
void transpose_bf16(const float* __restrict__ src, u16* __restrict__ dst,
                    int R, int C) {
  __shared__ float tile[64][65];
  const int t = threadIdx.x;
  const int rb = blockIdx.y << 6, cbs = blockIdx.x << 6;
  for (int i = 0; i < 16; ++i) {
    const int idx = t + (i << 8);
    const int r = idx >> 6, c = idx & 63;
    float v = 0.f;
    if (cbs + c < C) v = src[(size_t)(rb + r) * C + cbs + c];
    tile[r][c] = v;
  }
  __syncthreads();
  for (int i = 0; i < 16; ++i) {
    const int idx = t + (i << 8);
    const int c = idx >> 6, r = idx & 63;
    dst[(size_t)(cbs + c) * R + rb + r] = f2bf(tile[r][c]);
  }
}

// ---------------------------------------------------------------------------
// W_eff = (W + 2.0 * loraA @ loraB) * (W != 0), written TRANSPOSED as bf16:
// Wt[n][k] (4096 x 4096). K(lora)=64 fits one tile. grid = (64, 64).
// ---------------------------------------------------------------------------
__global__ __launch_bounds__(256)
void weff_kernel(const float* __restrict__ W, const float* __restrict__ lA,
                 const float* __restrict__ lB, u16* __restrict__ Wt) {
  __shared__ float at[64][65];   // at[k_local][r]
  __shared__ float bt[64][65];   // bt[n_local][r]
  __shared__ float wt[64][65];   // wt[k_local][n_local]
  const int t = threadIdx.x;
  const int kb = blockIdx.y << 6, nb = blockIdx.x << 6;
  for (int i = 0; i < 16; ++i) {
    const int idx = t + (i << 8);
    const int r0 = idx >> 6, c0 = idx & 63;
    at[r0][c0] = lA[(size_t)(kb + r0) * 64 + c0];          // A[k][r]
    bt[c0][r0] = lB[(size_t)r0 * 4096 + nb + c0];          // B[r][n] -> bt[n][r]
    wt[r0][c0] = W[(size_t)(kb + r0) * 4096 + nb + c0];
  }
  __syncthreads();
  const int tk = t & 15, tn = t >> 4;
  float s[4][4] = {};
  for (int r = 0; r < 64; ++r) {
    float a[4], b[4];
    for (int i = 0; i < 4; ++i) a[i] = at[tk * 4 + i][r];
    for (int j = 0; j < 4; ++j) b[j] = bt[tn * 4 + j][r];
    for (int i = 0; i < 4; ++i)
      for (int j = 0; j < 4; ++j)
        s[i][j] += a[i] * b[j];
  }
  for (int j = 0; j < 4; ++j) {
    const int nl = tn * 4 + j;
    u16 vals[4];
    for (int i = 0; i < 4; ++i) {
      const float wv = wt[tk * 4 + i][nl];
      const float res = (wv != 0.f) ? (wv + 2.0f * s[i][j]) : 0.f;
      vals[i] = f2bf(res);
    }
    ushort4 pack = make_ushort4(vals[0], vals[1], vals[2], vals[3]);
    *(ushort4*)&Wt[(size_t)(nb + nl) * 4096 + kb + tk * 4] = pack;
  }
}

// ---------------------------------------------------------------------------
// bf16 MFMA GEMM, 128x128 tile, BK=64, 256 threads, DOUBLE-BUFFERED LDS.
// R2: at 1 block/CU there is no inter-block overlap to hide the barrier's
// vmcnt(0) drain (m114 mechanism absent) -> prefetch tile kt+1 into the
// alternate buffer AFTER the barrier, compute on tile kt while DMA is in
// flight. One barrier per K-iter instead of two.
// EPI 0: relu(acc + bias[n]) -> outf (f32) + outb (bf16)      [E stage]
// EPI 1: relu(acc + st_in[m][n]) -> outf + outb               [recurrent]
// EPI 2: acc + bias[n] -> outf, guarded n < nvalid            [output]
// EPI 3: relu(acc + bias[n]) -> outb only                     [conv feat]
// ---------------------------------------------------------------------------
template<int EPI>
__global__ __launch_bounds__(256)
void gemm128(const u16* __restrict__ A, int lda,
             const u16* __restrict__ Bt, int ldb, int K,
             const float* __restrict__ bias,
             const float* __restrict__ st_in, int st_ld,
             float* __restrict__ outf, int outf_ld,
             u16* __restrict__ outb, int outb_ld, int nvalid) {
  __shared__ __align__(16) u16 As[2][128 * 64];
  __shared__ __align__(16) u16 Bs[2][128 * 64];
  const int t = threadIdx.x;
  const int w = t >> 6, lane = t & 63;
  const int mb = blockIdx.y << 7, nb = blockIdx.x << 7;
  const int m0 = (w & 1) << 6, n0 = (w >> 1) << 6;
  const int lr = lane & 15, lq = lane >> 4;

  f32x4 acc[4][4] = {};

  const int nk = K >> 6;

  // stage tile kt into buffer buf (1024 16B chunks per matrix; chunk c ->
  // LDS offset c*16, source row c>>3, k-chunk c&7; dest = wave-uniform base
  // + lane*16, as global_load_lds requires)
  auto stage = [&](int kt, int buf) {
    const int kb = kt << 6;
    for (int i = 0; i < 4; ++i) {
      const int c = (w << 8) + (i << 6) + lane;
      gl_lds16(A  + (size_t)(mb + (c >> 3)) * lda + kb + ((c & 7) << 3),
               (char*)As[buf] + c * 16);
      gl_lds16(Bt + (size_t)(nb + (c >> 3)) * ldb + kb + ((c & 7) << 3),
               (char*)Bs[buf] + c * 16);
    }
  };

  stage(0, 0);
  for (int kt = 0; kt < nk; ++kt) {
    const int buf = kt & 1;
    __syncthreads();               // drains tile kt's loads (issued 1 compute-phase ago)
    if (kt + 1 < nk) stage(kt + 1, buf ^ 1);
    for (int kk = 0; kk < 2; ++kk) {
      bf16x8 af[4], bf[4];
      for (int i = 0; i < 4; ++i)
        af[i] = *(const bf16x8*)&As[buf][(m0 + (i << 4) + lr) * 64 + (kk << 5) + (lq << 3)];
      for (int j = 0; j < 4; ++j)
        bf[j] = *(const bf16x8*)&Bs[buf][(n0 + (j << 4) + lr) * 64 + (kk << 5) + (lq << 3)];
      for (int i = 0; i < 4; ++i)
        for (int j = 0; j < 4; ++j)
          acc[i][j] = __builtin_amdgcn_mfma_f32_16x16x32_bf16(af[i], bf[j], acc[i][j], 0, 0, 0);
    }
  }

  // epilogue: C/D layout col = lane&15, row = (lane>>4)*4 + reg
  for (int i = 0; i < 4; ++i) {
    for (int j = 0; j < 4; ++j) {
      const int cg = nb + n0 + (j << 4) + lr;
      for (int r = 0; r < 4; ++r) {
        const int rg = mb + m0 + (i << 4) + (lq << 2) + r;
        float v = acc[i][j][r];
        if (EPI == 0) {
          v += bias[cg];
          v = v > 0.f ? v : 0.f;
          outf[(size_t)rg * outf_ld + cg] = v;
          outb[(size_t)rg * outb_ld + cg] = f2bf(v);
        } else if (EPI == 1) {
          v += st_in[(size_t)rg * st_ld + cg];
          v = v > 0.f ? v : 0.f;
          outf[(size_t)rg * outf_ld + cg] = v;
          outb[(size_t)rg * outb_ld + cg] = f2bf(v);
        } else if (EPI == 2) {
          if (cg < nvalid)
            outf[(size_t)rg * outf_ld + cg] = v + bias[cg];
        } else {
          v += bias[cg];
          v = v > 0.f ? v : 0.f;
          outb[(size_t)rg * outb_ld + cg] = f2bf(v);
        }
      }
    }
  }
}

// ---------------------------------------------------------------------------
extern "C" void kernel_launch(void* const* d_in, const int* in_sizes, int n_in,
                              void* d_out, int out_size, void* d_ws, size_t ws_size,
                              hipStream_t stream) {
  const float* x     = (const float*)d_in[0];
  const float* cw[8];
  for (int i = 0; i < 8; ++i) cw[i] = (const float*)d_in[1 + i];
  const float* convb = (const float*)d_in[9];
  const float* W     = (const float*)d_in[10];
  const float* lA    = (const float*)d_in[11];
  const float* lB    = (const float*)d_in[12];
  const float* ip_w  = (const float*)d_in[13];
  const float* ip_b  = (const float*)d_in[14];
  const float* out_w = (const float*)d_in[15];
  const float* out_b = (const float*)d_in[16];
  float* out = (float*)d_out;

  char* p = (char*)d_ws;
  u16* feat   = (u16*)p;  p += (size_t)1024 * 3328 * 2;   // lda 3328 (N padded)
  u16* ip_wt  = (u16*)p;  p += (size_t)1024 * 3264 * 2;
  u16* out_wt = (u16*)p;  p += (size_t)2048 * 1024 * 2;   // padded to 2048 rows
  u16* Wt     = (u16*)p;  p += (size_t)4096 * 4096 * 2;
  float* st_f[2];
  st_f[0] = (float*)p;    p += (size_t)1024 * 4096 * 4;
  st_f[1] = (float*)p;    p += (size_t)1024 * 4096 * 4;
  u16* st_b[2];
  st_b[0] = (u16*)p;      p += (size_t)1024 * 4096 * 2;
  st_b[1] = (u16*)p;      p += (size_t)1024 * 4096 * 2;

  // Conv-prep buffers alias st_f[1]: last read at the conv GEMM, st_f[1] is
  // first written at the t=1 recurrent GEMM (strictly later on the stream).
  char* q = (char*)st_f[1];
  u16* Xb       = (u16*)q;  q += (size_t)1024 * 512 * 2;
  u16* Wct      = (u16*)q;  q += (size_t)3328 * 512 * 2;
  float* bias_c = (float*)q;

  // --- conv prep: flatten x to bf16, build implicit-GEMM weight matrix ---
  x_to_bf16<<<512, 256, 0, stream>>>(x, Xb);
  hipMemsetAsync(Wct, 0, (size_t)3328 * 512 * 2, stream);
  hipMemsetAsync(bias_c, 0, (size_t)3328 * 4, stream);
  build_wc<<<3264, 256, 0, stream>>>(cw[0], cw[1], cw[2], cw[3],
                                     cw[4], cw[5], cw[6], cw[7], convb, Wct, bias_c);

  // --- weight transposes + W_eff ---
  transpose_bf16<<<dim3(16, 51), 256, 0, stream>>>(ip_w, ip_wt, 3264, 1024);
  transpose_bf16<<<dim3(32, 16), 256, 0, stream>>>(out_w, out_wt, 1024, 1968);
  weff_kernel<<<dim3(64, 64), 256, 0, stream>>>(W, lA, lB, Wt);

  hipMemsetAsync(st_f[0], 0, (size_t)1024 * 4096 * 4, stream);
  hipMemsetAsync(st_b[0], 0, (size_t)1024 * 4096 * 2, stream);

  // --- conv as MFMA GEMM: feat = relu(Xb @ Wc + bias_c), bf16 out ---
  gemm128<3><<<dim3(26, 8), 256, 0, stream>>>(Xb, 512, Wct, 512, 512,
      bias_c, nullptr, 0, nullptr, 0, feat, 3328, 3328);

  // t=0 collapses to state = relu(E_pad): E = feat @ ip_w + ip_b
  gemm128<0><<<dim3(8, 8), 256, 0, stream>>>(feat, 3328, ip_wt, 3264, 3264,
      ip_b, nullptr, 0, st_f[0], 4096, st_b[0], 4096, 1024);

  // t=1..4: state = relu(state + state @ W_eff), ping-pong buffers
  for (int ts = 1; ts <= 4; ++ts) {
    const int cur = (ts - 1) & 1, nxt = ts & 1;
    gemm128<1><<<dim3(32, 8), 256, 0, stream>>>(st_b[cur], 4096, Wt, 4096, 4096,
        nullptr, st_f[cur], 4096, st_f[nxt], 4096, st_b[nxt], 4096, 4096);
  }

  // output: state[:, 3072:] @ out_w + out_b  (final state in buffer 0)
  gemm128<2><<<dim3(16, 8), 256, 0, stream>>>(st_b[0] + 3072, 4096, out_wt, 1024, 1024,
      out_b, nullptr, 0, out, 1968, nullptr, 0, 1968);
}

// Round 4
// 569.065 us; speedup vs baseline: 2.0019x; 1.1304x over previous
//
#include <hip/hip_runtime.h>
#include <stdint.h>

typedef unsigned short u16;
typedef __attribute__((ext_vector_type(8))) short bf16x8;
typedef __attribute__((ext_vector_type(4))) float f32x4;

__device__ __forceinline__ u16 f2bf(float f) {
  union { float f; uint32_t u; } v; v.f = f;
  uint32_t u = v.u;
  return (u16)((u + 0x7fffu + ((u >> 16) & 1u)) >> 16);
}

__device__ __forceinline__ void gl_lds16(const void* g, void* l) {
  __builtin_amdgcn_global_load_lds(
      (const __attribute__((address_space(1))) uint32_t*)g,
      (__attribute__((address_space(3))) uint32_t*)l, 16, 0, 0);
}

__constant__ int c_off[9] = {0, 1024, 1808, 2384, 2784, 3040, 3184, 3248, 3264};

// ---------------------------------------------------------------------------
// x (1024 x 8 x 8 x 8 f32) -> Xb (1024 x 512 bf16). NHWC row-major flatten is
// exactly the GEMM K-layout k = (i*8+j)*8+c.
// ---------------------------------------------------------------------------
__global__ __launch_bounds__(256)
void x_to_bf16(const float* __restrict__ x, u16* __restrict__ Xb) {
  const int i = blockIdx.x * 256 + threadIdx.x;   // one float4 per thread
  const float4 v = ((const float4*)x)[i];
  ushort4 o = make_ushort4(f2bf(v.x), f2bf(v.y), f2bf(v.z), f2bf(v.w));
  ((ushort4*)Xb)[i] = o;
}

// ---------------------------------------------------------------------------
// Build the implicit-GEMM conv weight matrix, transposed/n-major:
// Wct[o][k] (3328 x 512 bf16, rows >= 3264 stay zero; pre-zeroed by memset).
// One block per output column o (R2: 13 blocks was latency-bound, 128us).
// ---------------------------------------------------------------------------
__global__ __launch_bounds__(256)
void build_wc(const float* w1, const float* w2, const float* w3, const float* w4,
              const float* w5, const float* w6, const float* w7, const float* w8,
              const float* __restrict__ cb,
              u16* __restrict__ Wct, float* __restrict__ bias_c) {
  const int o = blockIdx.x;
  const int t = threadIdx.x;
  const float* ws[8] = {w1, w2, w3, w4, w5, w6, w7, w8};
  int kidx = 0;
  while (o >= c_off[kidx + 1]) ++kidx;
  const int ks = kidx + 1;
  const int s  = 8 - kidx;
  const int r  = o - c_off[kidx];
  const int f   = r / (s * s);
  const int rem = r - f * s * s;
  const int oi  = rem / s;
  const int oj  = rem - oi * s;
  const float* w = ws[kidx] + (size_t)f * 8 * ks * ks;   // w[f][c][di][dj]
  u16* row = Wct + (size_t)o * 512;
  const int ne = 8 * ks * ks;
  for (int e = t; e < ne; e += 256) {
    const int c  = e / (ks * ks);
    const int er = e - c * ks * ks;
    const int di = er / ks;
    const int dj = er - di * ks;
    row[((oi + di) * 8 + (oj + dj)) * 8 + c] = f2bf(w[(c * ks + di) * ks + dj]);
  }
  if (t == 0) bias_c[o] = cb[kidx * 16 + f];
}

// ---------------------------------------------------------------------------
// Transpose + fp32->bf16 convert: src (R x C) f32 -> dst (Cp x R) bf16,
// zero-fill rows >= C. grid = (Cp/64, R/64).
// ---------------------------------------------------------------------------
__global__ __launch_bounds__(256)
void transpose_bf16(const float* __restrict__ src, u16* __restrict__ dst,
                    int R, int C) {
  __shared__ float tile[64][65];
  const int t = threadIdx.x;
  const int rb = blockIdx.y << 6, cbs = blockIdx.x << 6;
  for (int i = 0; i < 16; ++i) {
    const int idx = t + (i << 8);
    const int r = idx >> 6, c = idx & 63;
    float v = 0.f;
    if (cbs + c < C) v = src[(size_t)(rb + r) * C + cbs + c];
    tile[r][c] = v;
  }
  __syncthreads();
  for (int i = 0; i < 16; ++i) {
    const int idx = t + (i << 8);
    const int c = idx >> 6, r = idx & 63;
    dst[(size_t)(cbs + c) * R + rb + r] = f2bf(tile[r][c]);
  }
}

// ---------------------------------------------------------------------------
// W_eff = (W + 2.0 * loraA @ loraB) * (W != 0), written TRANSPOSED as bf16:
// Wt[n][k] (4096 x 4096). K(lora)=64 fits one tile. grid = (64, 64).
// ---------------------------------------------------------------------------
__global__ __launch_bounds__(256)
void weff_kernel(const float* __restrict__ W, const float* __restrict__ lA,
                 const float* __restrict__ lB, u16* __restrict__ Wt) {
  __shared__ float at[64][65];   // at[k_local][r]
  __shared__ float bt[64][65];   // bt[n_local][r]
  __shared__ float wt[64][65];   // wt[k_local][n_local]
  const int t = threadIdx.x;
  const int kb = blockIdx.y << 6, nb = blockIdx.x << 6;
  for (int i = 0; i < 16; ++i) {
    const int idx = t + (i << 8);
    const int r0 = idx >> 6, c0 = idx & 63;
    at[r0][c0] = lA[(size_t)(kb + r0) * 64 + c0];          // A[k][r]
    bt[c0][r0] = lB[(size_t)r0 * 4096 + nb + c0];          // B[r][n] -> bt[n][r]
    wt[r0][c0] = W[(size_t)(kb + r0) * 4096 + nb + c0];
  }
  __syncthreads();
  const int tk = t & 15, tn = t >> 4;
  float s[4][4] = {};
  for (int r = 0; r < 64; ++r) {
    float a[4], b[4];
    for (int i = 0; i < 4; ++i) a[i] = at[tk * 4 + i][r];
    for (int j = 0; j < 4; ++j) b[j] = bt[tn * 4 + j][r];
    for (int i = 0; i < 4; ++i)
      for (int j = 0; j < 4; ++j)
        s[i][j] += a[i] * b[j];
  }
  for (int j = 0; j < 4; ++j) {
    const int nl = tn * 4 + j;
    u16 vals[4];
    for (int i = 0; i < 4; ++i) {
      const float wv = wt[tk * 4 + i][nl];
      const float res = (wv != 0.f) ? (wv + 2.0f * s[i][j]) : 0.f;
      vals[i] = f2bf(res);
    }
    ushort4 pack = make_ushort4(vals[0], vals[1], vals[2], vals[3]);
    *(ushort4*)&Wt[(size_t)(nb + nl) * 4096 + kb + tk * 4] = pack;
  }
}

// ---------------------------------------------------------------------------
// bf16 MFMA GEMM, 128x128 tile, BK=64, 256 threads, double-buffered LDS,
// XOR-SWIZZLED LDS layout (R3): element (row, kg) lives at 16B-slot
// row*8 + (kg ^ (row&7)). Staging stays contiguous (global_load_lds
// requirement) by permuting the SOURCE k-octet instead; fragment reads then
// spread each quarter-wave across all 8 bank groups -> conflict-free b128.
// (R2 layout had row stride 128 B = 32 banks: 16 lanes hit one 4-bank group,
// 16-way conflict, SQ_LDS_BANK_CONFLICT = 1.26e7/dispatch.)
// EPI 0: relu(acc + bias[n]) -> outf (f32) + outb (bf16)      [E stage]
// EPI 1: relu(acc + st_in[m][n]) -> outf + outb               [recurrent]
// EPI 2: acc + bias[n] -> outf, guarded n < nvalid            [output]
// EPI 3: relu(acc + bias[n]) -> outb only                     [conv feat]
// ---------------------------------------------------------------------------
template<int EPI>
__global__ __launch_bounds__(256)
void gemm128(const u16* __restrict__ A, int lda,
             const u16* __restrict__ Bt, int ldb, int K,
             const float* __restrict__ bias,
             const float* __restrict__ st_in, int st_ld,
             float* __restrict__ outf, int outf_ld,
             u16* __restrict__ outb, int outb_ld, int nvalid) {
  __shared__ __align__(16) u16 As[2][128 * 64];
  __shared__ __align__(16) u16 Bs[2][128 * 64];
  const int t = threadIdx.x;
  const int w = t >> 6, lane = t & 63;
  const int mb = blockIdx.y << 7, nb = blockIdx.x << 7;
  const int m0 = (w & 1) << 6, n0 = (w >> 1) << 6;
  const int lr = lane & 15, lq = lane >> 4;

  f32x4 acc[4][4] = {};

  const int nk = K >> 6;

  // stage tile kt into buffer buf: chunk c -> LDS offset c*16 (contiguous,
  // wave-uniform base + lane*16). Source row = c>>3; source k-octet is
  // XOR-permuted: kg_src = (c&7) ^ (row&7) -- same 128B global row, so
  // coalescing is preserved while realizing the swizzled layout.
  auto stage = [&](int kt, int buf) {
    const int kb = kt << 6;
    for (int i = 0; i < 4; ++i) {
      const int c   = (w << 8) + (i << 6) + lane;
      const int row = c >> 3;
      const int kg  = (c & 7) ^ (row & 7);
      gl_lds16(A  + (size_t)(mb + row) * lda + kb + (kg << 3),
               (char*)As[buf] + c * 16);
      gl_lds16(Bt + (size_t)(nb + row) * ldb + kb + (kg << 3),
               (char*)Bs[buf] + c * 16);
    }
  };

  stage(0, 0);
  for (int kt = 0; kt < nk; ++kt) {
    const int buf = kt & 1;
    __syncthreads();               // drains tile kt's loads (issued 1 compute-phase ago)
    if (kt + 1 < nk) stage(kt + 1, buf ^ 1);
    for (int kk = 0; kk < 2; ++kk) {
      const int kg = (kk << 2) + lq;           // k-octet this lane reads
      const int sw = (kg ^ (lr & 7)) << 3;     // swizzled column offset (u16)
      bf16x8 af[4], bf[4];
      for (int i = 0; i < 4; ++i)
        af[i] = *(const bf16x8*)&As[buf][(m0 + (i << 4) + lr) * 64 + sw];
      for (int j = 0; j < 4; ++j)
        bf[j] = *(const bf16x8*)&Bs[buf][(n0 + (j << 4) + lr) * 64 + sw];
      for (int i = 0; i < 4; ++i)
        for (int j = 0; j < 4; ++j)
          acc[i][j] = __builtin_amdgcn_mfma_f32_16x16x32_bf16(af[i], bf[j], acc[i][j], 0, 0, 0);
    }
  }

  // epilogue: C/D layout col = lane&15, row = (lane>>4)*4 + reg
  for (int i = 0; i < 4; ++i) {
    for (int j = 0; j < 4; ++j) {
      const int cg = nb + n0 + (j << 4) + lr;
      for (int r = 0; r < 4; ++r) {
        const int rg = mb + m0 + (i << 4) + (lq << 2) + r;
        float v = acc[i][j][r];
        if (EPI == 0) {
          v += bias[cg];
          v = v > 0.f ? v : 0.f;
          outf[(size_t)rg * outf_ld + cg] = v;
          outb[(size_t)rg * outb_ld + cg] = f2bf(v);
        } else if (EPI == 1) {
          v += st_in[(size_t)rg * st_ld + cg];
          v = v > 0.f ? v : 0.f;
          outf[(size_t)rg * outf_ld + cg] = v;
          outb[(size_t)rg * outb_ld + cg] = f2bf(v);
        } else if (EPI == 2) {
          if (cg < nvalid)
            outf[(size_t)rg * outf_ld + cg] = v + bias[cg];
        } else {
          v += bias[cg];
          v = v > 0.f ? v : 0.f;
          outb[(size_t)rg * outb_ld + cg] = f2bf(v);
        }
      }
    }
  }
}

// ---------------------------------------------------------------------------
extern "C" void kernel_launch(void* const* d_in, const int* in_sizes, int n_in,
                              void* d_out, int out_size, void* d_ws, size_t ws_size,
                              hipStream_t stream) {
  const float* x     = (const float*)d_in[0];
  const float* cw[8];
  for (int i = 0; i < 8; ++i) cw[i] = (const float*)d_in[1 + i];
  const float* convb = (const float*)d_in[9];
  const float* W     = (const float*)d_in[10];
  const float* lA    = (const float*)d_in[11];
  const float* lB    = (const float*)d_in[12];
  const float* ip_w  = (const float*)d_in[13];
  const float* ip_b  = (const float*)d_in[14];
  const float* out_w = (const float*)d_in[15];
  const float* out_b = (const float*)d_in[16];
  float* out = (float*)d_out;

  char* p = (char*)d_ws;
  u16* feat   = (u16*)p;  p += (size_t)1024 * 3328 * 2;   // lda 3328 (N padded)
  u16* ip_wt  = (u16*)p;  p += (size_t)1024 * 3264 * 2;
  u16* out_wt = (u16*)p;  p += (size_t)2048 * 1024 * 2;   // padded to 2048 rows
  u16* Wt     = (u16*)p;  p += (size_t)4096 * 4096 * 2;
  float* st_f[2];
  st_f[0] = (float*)p;    p += (size_t)1024 * 4096 * 4;
  st_f[1] = (float*)p;    p += (size_t)1024 * 4096 * 4;
  u16* st_b[2];
  st_b[0] = (u16*)p;      p += (size_t)1024 * 4096 * 2;
  st_b[1] = (u16*)p;      p += (size_t)1024 * 4096 * 2;

  // Conv-prep buffers alias st_f[1]: last read at the conv GEMM, st_f[1] is
  // first written at the t=1 recurrent GEMM (strictly later on the stream).
  char* q = (char*)st_f[1];
  u16* Xb       = (u16*)q;  q += (size_t)1024 * 512 * 2;
  u16* Wct      = (u16*)q;  q += (size_t)3328 * 512 * 2;
  float* bias_c = (float*)q;

  // --- conv prep: flatten x to bf16, build implicit-GEMM weight matrix ---
  x_to_bf16<<<512, 256, 0, stream>>>(x, Xb);
  hipMemsetAsync(Wct, 0, (size_t)3328 * 512 * 2, stream);
  hipMemsetAsync(bias_c, 0, (size_t)3328 * 4, stream);
  build_wc<<<3264, 256, 0, stream>>>(cw[0], cw[1], cw[2], cw[3],
                                     cw[4], cw[5], cw[6], cw[7], convb, Wct, bias_c);

  // --- weight transposes + W_eff ---
  transpose_bf16<<<dim3(16, 51), 256, 0, stream>>>(ip_w, ip_wt, 3264, 1024);
  transpose_bf16<<<dim3(32, 16), 256, 0, stream>>>(out_w, out_wt, 1024, 1968);
  weff_kernel<<<dim3(64, 64), 256, 0, stream>>>(W, lA, lB, Wt);

  hipMemsetAsync(st_f[0], 0, (size_t)1024 * 4096 * 4, stream);
  hipMemsetAsync(st_b[0], 0, (size_t)1024 * 4096 * 2, stream);

  // --- conv as MFMA GEMM: feat = relu(Xb @ Wc + bias_c), bf16 out ---
  gemm128<3><<<dim3(26, 8), 256, 0, stream>>>(Xb, 512, Wct, 512, 512,
      bias_c, nullptr, 0, nullptr, 0, feat, 3328, 3328);

  // t=0 collapses to state = relu(E_pad): E = feat @ ip_w + ip_b
  gemm128<0><<<dim3(8, 8), 256, 0, stream>>>(feat, 3328, ip_wt, 3264, 3264,
      ip_b, nullptr, 0, st_f[0], 4096, st_b[0], 4096, 1024);

  // t=1..4: state = relu(state + state @ W_eff), ping-pong buffers
  for (int ts = 1; ts <= 4; ++ts) {
    const int cur = (ts - 1) & 1, nxt = ts & 1;
    gemm128<1><<<dim3(32, 8), 256, 0, stream>>>(st_b[cur], 4096, Wt, 4096, 4096,
        nullptr, st_f[cur], 4096, st_f[nxt], 4096, st_b[nxt], 4096, 4096);
  }

  // output: state[:, 3072:] @ out_w + out_b  (final state in buffer 0)
  gemm128<2><<<dim3(16, 8), 256, 0, stream>>>(st_b[0] + 3072, 4096, out_wt, 1024, 1024,
      out_b, nullptr, 0, out, 1968, nullptr, 0, 1968);
}

// Round 5
// 495.900 us; speedup vs baseline: 2.2973x; 1.1475x over previous
//
#include <hip/hip_runtime.h>
#include <stdint.h>

typedef unsigned short u16;
typedef __attribute__((ext_vector_type(8))) short bf16x8;
typedef __attribute__((ext_vector_type(4))) float f32x4;

__device__ __forceinline__ u16 f2bf(float f) {
  union { float f; uint32_t u; } v; v.f = f;
  uint32_t u = v.u;
  return (u16)((u + 0x7fffu + ((u >> 16) & 1u)) >> 16);
}

__device__ __forceinline__ void gl_lds16(const void* g, void* l) {
  __builtin_amdgcn_global_load_lds(
      (const __attribute__((address_space(1))) uint32_t*)g,
      (__attribute__((address_space(3))) uint32_t*)l, 16, 0, 0);
}

__constant__ int c_off[9] = {0, 1024, 1808, 2384, 2784, 3040, 3184, 3248, 3264};

// ---------------------------------------------------------------------------
// x (1024 x 8 x 8 x 8 f32) -> Xb (1024 x 512 bf16). NHWC row-major flatten is
// exactly the GEMM K-layout k = (i*8+j)*8+c.
// ---------------------------------------------------------------------------
__global__ __launch_bounds__(256)
void x_to_bf16(const float* __restrict__ x, u16* __restrict__ Xb) {
  const int i = blockIdx.x * 256 + threadIdx.x;   // one float4 per thread
  const float4 v = ((const float4*)x)[i];
  ushort4 o = make_ushort4(f2bf(v.x), f2bf(v.y), f2bf(v.z), f2bf(v.w));
  ((ushort4*)Xb)[i] = o;
}

// ---------------------------------------------------------------------------
// Build the implicit-GEMM conv weight matrix, transposed/n-major:
// Wct[o][k] (3328 x 512 bf16, rows >= 3264 stay zero; pre-zeroed by memset).
// One block per output column o (R2: 13 blocks was latency-bound, 128us).
// ---------------------------------------------------------------------------
__global__ __launch_bounds__(256)
void build_wc(const float* w1, const float* w2, const float* w3, const float* w4,
              const float* w5, const float* w6, const float* w7, const float* w8,
              const float* __restrict__ cb,
              u16* __restrict__ Wct, float* __restrict__ bias_c) {
  const int o = blockIdx.x;
  const int t = threadIdx.x;
  const float* ws[8] = {w1, w2, w3, w4, w5, w6, w7, w8};
  int kidx = 0;
  while (o >= c_off[kidx + 1]) ++kidx;
  const int ks = kidx + 1;
  const int s  = 8 - kidx;
  const int r  = o - c_off[kidx];
  const int f   = r / (s * s);
  const int rem = r - f * s * s;
  const int oi  = rem / s;
  const int oj  = rem - oi * s;
  const float* w = ws[kidx] + (size_t)f * 8 * ks * ks;   // w[f][c][di][dj]
  u16* row = Wct + (size_t)o * 512;
  const int ne = 8 * ks * ks;
  for (int e = t; e < ne; e += 256) {
    const int c  = e / (ks * ks);
    const int er = e - c * ks * ks;
    const int di = er / ks;
    const int dj = er - di * ks;
    row[((oi + di) * 8 + (oj + dj)) * 8 + c] = f2bf(w[(c * ks + di) * ks + dj]);
  }
  if (t == 0) bias_c[o] = cb[kidx * 16 + f];
}

// ---------------------------------------------------------------------------
// Transpose + fp32->bf16 convert: src (R x C) f32 -> dst (Cp x R) bf16,
// zero-fill rows >= C. grid = (Cp/64, R/64).
// ---------------------------------------------------------------------------
__global__ __launch_bounds__(256)
void transpose_bf16(const float* __restrict__ src, u16* __restrict__ dst,
                    int R, int C) {
  __shared__ float tile[64][65];
  const int t = threadIdx.x;
  const int rb = blockIdx.y << 6, cbs = blockIdx.x << 6;
  for (int i = 0; i < 16; ++i) {
    const int idx = t + (i << 8);
    const int r = idx >> 6, c = idx & 63;
    float v = 0.f;
    if (cbs + c < C) v = src[(size_t)(rb + r) * C + cbs + c];
    tile[r][c] = v;
  }
  __syncthreads();
  for (int i = 0; i < 16; ++i) {
    const int idx = t + (i << 8);
    const int c = idx >> 6, r = idx & 63;
    dst[(size_t)(cbs + c) * R + rb + r] = f2bf(tile[r][c]);
  }
}

// ---------------------------------------------------------------------------
// W_eff = (W + 2.0 * loraA @ loraB) * (W != 0), written TRANSPOSED as bf16:
// Wt[n][k] (4096 x 4096). K(lora)=64 fits one tile. grid = (64, 64).
// ---------------------------------------------------------------------------
__global__ __launch_bounds__(256)
void weff_kernel(const float* __restrict__ W, const float* __restrict__ lA,
                 const float* __restrict__ lB, u16* __restrict__ Wt) {
  __shared__ float at[64][65];   // at[k_local][r]
  __shared__ float bt[64][65];   // bt[n_local][r]
  __shared__ float wt[64][65];   // wt[k_local][n_local]
  const int t = threadIdx.x;
  const int kb = blockIdx.y << 6, nb = blockIdx.x << 6;
  for (int i = 0; i < 16; ++i) {
    const int idx = t + (i << 8);
    const int r0 = idx >> 6, c0 = idx & 63;
    at[r0][c0] = lA[(size_t)(kb + r0) * 64 + c0];          // A[k][r]
    bt[c0][r0] = lB[(size_t)r0 * 4096 + nb + c0];          // B[r][n] -> bt[n][r]
    wt[r0][c0] = W[(size_t)(kb + r0) * 4096 + nb + c0];
  }
  __syncthreads();
  const int tk = t & 15, tn = t >> 4;
  float s[4][4] = {};
  for (int r = 0; r < 64; ++r) {
    float a[4], b[4];
    for (int i = 0; i < 4; ++i) a[i] = at[tk * 4 + i][r];
    for (int j = 0; j < 4; ++j) b[j] = bt[tn * 4 + j][r];
    for (int i = 0; i < 4; ++i)
      for (int j = 0; j < 4; ++j)
        s[i][j] += a[i] * b[j];
  }
  for (int j = 0; j < 4; ++j) {
    const int nl = tn * 4 + j;
    u16 vals[4];
    for (int i = 0; i < 4; ++i) {
      const float wv = wt[tk * 4 + i][nl];
      const float res = (wv != 0.f) ? (wv + 2.0f * s[i][j]) : 0.f;
      vals[i] = f2bf(res);
    }
    ushort4 pack = make_ushort4(vals[0], vals[1], vals[2], vals[3]);
    *(ushort4*)&Wt[(size_t)(nb + nl) * 4096 + kb + tk * 4] = pack;
  }
}

// ---------------------------------------------------------------------------
// bf16 MFMA GEMM, 64x128 block tile (R4: was 128x128 -> grid 256 = 1 block/CU
// = 1 wave/SIMD, zero latency overlap, MfmaUtil 17.7%. 64x128 doubles the
// grid to 2 blocks/CU; each SIMD hosts 2 waves from DIFFERENT blocks with
// independent barriers -> m114-style MFMA/stall overlap). BK=64, 256 threads,
// double-buffered LDS (48 KB), XOR-swizzled layout (R3: conflict-free).
// Wave tile 32x64: acc[2][4], 2 A-frags x 4 B-frags per kk.
// EPI 0: relu(acc + bias[n]) -> outf (f32) + outb (bf16)      [E stage]
// EPI 1: relu(acc + st_in[m][n]) -> outf + outb               [recurrent]
// EPI 2: acc + bias[n] -> outf, guarded n < nvalid            [output]
// EPI 3: relu(acc + bias[n]) -> outb only                     [conv feat]
// ---------------------------------------------------------------------------
template<int EPI>
__global__ __launch_bounds__(256)
void gemm128(const u16* __restrict__ A, int lda,
             const u16* __restrict__ Bt, int ldb, int K,
             const float* __restrict__ bias,
             const float* __restrict__ st_in, int st_ld,
             float* __restrict__ outf, int outf_ld,
             u16* __restrict__ outb, int outb_ld, int nvalid) {
  __shared__ __align__(16) u16 As[2][64 * 64];
  __shared__ __align__(16) u16 Bs[2][128 * 64];
  const int t = threadIdx.x;
  const int w = t >> 6, lane = t & 63;
  const int mb = blockIdx.y << 6, nb = blockIdx.x << 7;
  const int m0 = (w & 1) << 5, n0 = (w >> 1) << 6;
  const int lr = lane & 15, lq = lane >> 4;

  f32x4 acc[2][4] = {};

  const int nk = K >> 6;

  // stage tile kt into buffer buf: chunk c -> LDS slot c*16 (contiguous,
  // wave-uniform base + lane*16, as global_load_lds requires). Source row =
  // c>>3; source k-octet XOR-permuted (kg = (c&7) ^ (row&7)) so the LDS
  // layout is swizzled while global reads stay within one 128B row.
  auto stage = [&](int kt, int buf) {
    const int kb = kt << 6;
    for (int i = 0; i < 2; ++i) {                 // A: 512 chunks (64 rows)
      const int c   = (w << 7) + (i << 6) + lane;
      const int row = c >> 3;
      const int kg  = (c & 7) ^ (row & 7);
      gl_lds16(A + (size_t)(mb + row) * lda + kb + (kg << 3),
               (char*)As[buf] + c * 16);
    }
    for (int i = 0; i < 4; ++i) {                 // B: 1024 chunks (128 rows)
      const int c   = (w << 8) + (i << 6) + lane;
      const int row = c >> 3;
      const int kg  = (c & 7) ^ (row & 7);
      gl_lds16(Bt + (size_t)(nb + row) * ldb + kb + (kg << 3),
               (char*)Bs[buf] + c * 16);
    }
  };

  stage(0, 0);
  for (int kt = 0; kt < nk; ++kt) {
    const int buf = kt & 1;
    __syncthreads();               // drains tile kt's loads (issued 1 compute-phase ago)
    if (kt + 1 < nk) stage(kt + 1, buf ^ 1);
    for (int kk = 0; kk < 2; ++kk) {
      const int kg = (kk << 2) + lq;           // k-octet this lane reads
      const int sw = (kg ^ (lr & 7)) << 3;     // swizzled column offset (u16)
      bf16x8 af[2], bf[4];
      for (int i = 0; i < 2; ++i)
        af[i] = *(const bf16x8*)&As[buf][(m0 + (i << 4) + lr) * 64 + sw];
      for (int j = 0; j < 4; ++j)
        bf[j] = *(const bf16x8*)&Bs[buf][(n0 + (j << 4) + lr) * 64 + sw];
      for (int i = 0; i < 2; ++i)
        for (int j = 0; j < 4; ++j)
          acc[i][j] = __builtin_amdgcn_mfma_f32_16x16x32_bf16(af[i], bf[j], acc[i][j], 0, 0, 0);
    }
  }

  // epilogue: C/D layout col = lane&15, row = (lane>>4)*4 + reg
  for (int i = 0; i < 2; ++i) {
    for (int j = 0; j < 4; ++j) {
      const int cg = nb + n0 + (j << 4) + lr;
      for (int r = 0; r < 4; ++r) {
        const int rg = mb + m0 + (i << 4) + (lq << 2) + r;
        float v = acc[i][j][r];
        if (EPI == 0) {
          v += bias[cg];
          v = v > 0.f ? v : 0.f;
          outf[(size_t)rg * outf_ld + cg] = v;
          outb[(size_t)rg * outb_ld + cg] = f2bf(v);
        } else if (EPI == 1) {
          v += st_in[(size_t)rg * st_ld + cg];
          v = v > 0.f ? v : 0.f;
          outf[(size_t)rg * outf_ld + cg] = v;
          outb[(size_t)rg * outb_ld + cg] = f2bf(v);
        } else if (EPI == 2) {
          if (cg < nvalid)
            outf[(size_t)rg * outf_ld + cg] = v + bias[cg];
        } else {
          v += bias[cg];
          v = v > 0.f ? v : 0.f;
          outb[(size_t)rg * outb_ld + cg] = f2bf(v);
        }
      }
    }
  }
}

// ---------------------------------------------------------------------------
extern "C" void kernel_launch(void* const* d_in, const int* in_sizes, int n_in,
                              void* d_out, int out_size, void* d_ws, size_t ws_size,
                              hipStream_t stream) {
  const float* x     = (const float*)d_in[0];
  const float* cw[8];
  for (int i = 0; i < 8; ++i) cw[i] = (const float*)d_in[1 + i];
  const float* convb = (const float*)d_in[9];
  const float* W     = (const float*)d_in[10];
  const float* lA    = (const float*)d_in[11];
  const float* lB    = (const float*)d_in[12];
  const float* ip_w  = (const float*)d_in[13];
  const float* ip_b  = (const float*)d_in[14];
  const float* out_w = (const float*)d_in[15];
  const float* out_b = (const float*)d_in[16];
  float* out = (float*)d_out;

  char* p = (char*)d_ws;
  u16* feat   = (u16*)p;  p += (size_t)1024 * 3328 * 2;   // lda 3328 (N padded)
  u16* ip_wt  = (u16*)p;  p += (size_t)1024 * 3264 * 2;
  u16* out_wt = (u16*)p;  p += (size_t)2048 * 1024 * 2;   // padded to 2048 rows
  u16* Wt     = (u16*)p;  p += (size_t)4096 * 4096 * 2;
  float* st_f[2];
  st_f[0] = (float*)p;    p += (size_t)1024 * 4096 * 4;
  st_f[1] = (float*)p;    p += (size_t)1024 * 4096 * 4;
  u16* st_b[2];
  st_b[0] = (u16*)p;      p += (size_t)1024 * 4096 * 2;
  st_b[1] = (u16*)p;      p += (size_t)1024 * 4096 * 2;

  // Conv-prep buffers alias st_f[1]: last read at the conv GEMM, st_f[1] is
  // first written at the t=1 recurrent GEMM (strictly later on the stream).
  char* q = (char*)st_f[1];
  u16* Xb       = (u16*)q;  q += (size_t)1024 * 512 * 2;
  u16* Wct      = (u16*)q;  q += (size_t)3328 * 512 * 2;
  float* bias_c = (float*)q;

  // --- conv prep: flatten x to bf16, build implicit-GEMM weight matrix ---
  x_to_bf16<<<512, 256, 0, stream>>>(x, Xb);
  hipMemsetAsync(Wct, 0, (size_t)3328 * 512 * 2, stream);
  hipMemsetAsync(bias_c, 0, (size_t)3328 * 4, stream);
  build_wc<<<3264, 256, 0, stream>>>(cw[0], cw[1], cw[2], cw[3],
                                     cw[4], cw[5], cw[6], cw[7], convb, Wct, bias_c);

  // --- weight transposes + W_eff ---
  transpose_bf16<<<dim3(16, 51), 256, 0, stream>>>(ip_w, ip_wt, 3264, 1024);
  transpose_bf16<<<dim3(32, 16), 256, 0, stream>>>(out_w, out_wt, 1024, 1968);
  weff_kernel<<<dim3(64, 64), 256, 0, stream>>>(W, lA, lB, Wt);

  hipMemsetAsync(st_f[0], 0, (size_t)1024 * 4096 * 4, stream);
  hipMemsetAsync(st_b[0], 0, (size_t)1024 * 4096 * 2, stream);

  // --- conv as MFMA GEMM: feat = relu(Xb @ Wc + bias_c), bf16 out ---
  gemm128<3><<<dim3(26, 16), 256, 0, stream>>>(Xb, 512, Wct, 512, 512,
      bias_c, nullptr, 0, nullptr, 0, feat, 3328, 3328);

  // t=0 collapses to state = relu(E_pad): E = feat @ ip_w + ip_b
  gemm128<0><<<dim3(8, 16), 256, 0, stream>>>(feat, 3328, ip_wt, 3264, 3264,
      ip_b, nullptr, 0, st_f[0], 4096, st_b[0], 4096, 1024);

  // t=1..4: state = relu(state + state @ W_eff), ping-pong buffers
  for (int ts = 1; ts <= 4; ++ts) {
    const int cur = (ts - 1) & 1, nxt = ts & 1;
    gemm128<1><<<dim3(32, 16), 256, 0, stream>>>(st_b[cur], 4096, Wt, 4096, 4096,
        nullptr, st_f[cur], 4096, st_f[nxt], 4096, st_b[nxt], 4096, 4096);
  }

  // output: state[:, 3072:] @ out_w + out_b  (final state in buffer 0)
  gemm128<2><<<dim3(16, 16), 256, 0, stream>>>(st_b[0] + 3072, 4096, out_wt, 1024, 1024,
      out_b, nullptr, 0, out, 1968, nullptr, 0, 1968);
}